// Round 15
// baseline (118.694 us; speedup 1.0000x reference)
//
#include <hip/hip_runtime.h>

#define T_DIM 2000
#define N_DIM 128
#define IN_DIM 256
#define OUT_C 46
#define NROWS (T_DIM * N_DIM)
#define NCHUNK 250
#define CLEN 8
#define NSUPER 25
#define SLEN 10

typedef short bf16x8 __attribute__((ext_vector_type(8)));
typedef float f32x4 __attribute__((ext_vector_type(4)));

union F8U { bf16x8 v; uint32_t u[4]; };

__device__ __forceinline__ uint32_t cvtpk(float lo, float hi) {
  uint32_t r;
  asm("v_cvt_pk_bf16_f32 %0, %1, %2" : "=v"(r) : "v"(lo), "v"(hi));
  return r;
}

__device__ __forceinline__ float bf2f(unsigned short u) {
  uint32_t w = (uint32_t)u << 16;
  return __builtin_bit_cast(float, w);
}

#define LDSK 264  // padded W row length (shorts)
#define YPAD 132  // padded Yst row length (shorts)

// ---------------------------------------------------------------------------
// k1: y = x @ W^T + b via MFMA 16x16x32 bf16 (W in LDS bf16, half-tile
// ping-pong A prefetch, plain cached x loads).  Trans scores staged in
// padded LDS Yst and flushed fully-coalesced.  (R12 structure, 100us.)
// ---------------------------------------------------------------------------
__global__ __launch_bounds__(256, 3) void k1_gemm(const float* __restrict__ x,
                                                  const float* __restrict__ W,
                                                  const float* __restrict__ b,
                                                  unsigned short* __restrict__ wsYT,
                                                  float* __restrict__ wsMod) {
  __shared__ unsigned short Wl[43 * LDSK];    // 22.7 KB
  __shared__ unsigned short Yst[2 * 40 * YPAD]; // 21.1 KB
  const int tid  = threadIdx.x;
  const int lane = tid & 63;
  const int wv   = tid >> 6;
  const int ln   = lane & 15;
  const int lh   = lane >> 4;

  {  // stage W as bf16 into padded LDS rows
    uint32_t* Wd = reinterpret_cast<uint32_t*>(Wl);
#pragma unroll
    for (int it = 0; it < 22; ++it) {
      int e = tid + it * 256;
      if (e < 43 * 128) {
        int n = e >> 7, kp = e & 127;
        float2 w = *reinterpret_cast<const float2*>(W + (size_t)n * IN_DIM + 2 * kp);
        Wd[n * (LDSK / 2) + kp] = cvtpk(w.x, w.y);
      }
    }
  }
  float bias[3];
#pragma unroll
  for (int nt = 0; nt < 3; ++nt) {
    int n = nt * 16 + ln;
    bias[nt] = b[n > 42 ? 42 : n];
  }
  __syncthreads();

  const int rowbase = blockIdx.x * 256 + wv * 64;
  const float* xbase = x + (size_t)(rowbase + ln) * IN_DIM + lh * 8;

  f32x4 bufA[8], bufB[8];
  f32x4 zero = {0.f, 0.f, 0.f, 0.f};
  f32x4 acc[3] = {zero, zero, zero};

#define LOADH(BUF, T, HF) do {                                               \
    const float* _p = xbase + (size_t)(T) * (16 * IN_DIM) + (HF) * 128;      \
    _Pragma("unroll")                                                        \
    for (int _s = 0; _s < 4; ++_s) {                                         \
      BUF[_s]     = *reinterpret_cast<const f32x4*>(_p + _s * 32);           \
      BUF[_s + 4] = *reinterpret_cast<const f32x4*>(_p + _s * 32 + 4);       \
    }                                                                        \
  } while (0)

#define COMPH(BUF, HF) do {                                                  \
    _Pragma("unroll")                                                        \
    for (int _s2 = 0; _s2 < 4; ++_s2) {                                      \
      F8U _af;                                                               \
      _af.u[0] = cvtpk(BUF[_s2].x, BUF[_s2].y);                              \
      _af.u[1] = cvtpk(BUF[_s2].z, BUF[_s2].w);                              \
      _af.u[2] = cvtpk(BUF[_s2 + 4].x, BUF[_s2 + 4].y);                      \
      _af.u[3] = cvtpk(BUF[_s2 + 4].z, BUF[_s2 + 4].w);                      \
      const int _s = (HF) * 4 + _s2;                                         \
      _Pragma("unroll")                                                      \
      for (int _nt = 0; _nt < 3; ++_nt) {                                    \
        const bf16x8 _bf = *reinterpret_cast<const bf16x8*>(                 \
            &Wl[(_nt * 16 + ln) * LDSK + _s * 32 + lh * 8]);                 \
        acc[_nt] = __builtin_amdgcn_mfma_f32_16x16x32_bf16(_af.v, _bf,       \
                                                           acc[_nt], 0, 0, 0);\
      }                                                                      \
    }                                                                        \
  } while (0)

  LOADH(bufA, 0, 0);
  LOADH(bufB, 0, 1);
#pragma unroll 1
  for (int t = 0; t < 4; ++t) {
    COMPH(bufA, 0);
    if (t < 3) LOADH(bufA, t + 1, 0);
    COMPH(bufB, 1);
    if (t < 3) LOADH(bufB, t + 1, 1);
    const int R0   = rowbase + t * 16;
    const int tloc = (R0 >> 7) & 1;
    const int n0   = (R0 & 127) + lh * 4;
#pragma unroll
    for (int nt = 0; nt < 3; ++nt) {
      if (nt < 2 || ln < 8) {
        const int c = nt * 16 + ln;
        uint32_t d0 = cvtpk(acc[nt][0] + bias[nt], acc[nt][1] + bias[nt]);
        uint32_t d1 = cvtpk(acc[nt][2] + bias[nt], acc[nt][3] + bias[nt]);
        uint2 v; v.x = d0; v.y = d1;
        *reinterpret_cast<uint2*>(&Yst[(tloc * 40 + c) * YPAD + n0]) = v;
      } else if (ln < 11) {
        const int tt = R0 >> 7;
        float4 v;
        v.x = acc[2][0] + bias[2]; v.y = acc[2][1] + bias[2];
        v.z = acc[2][2] + bias[2]; v.w = acc[2][3] + bias[2];
        *reinterpret_cast<float4*>(
            wsMod + ((size_t)tt * 3 + (ln - 8)) * 128 + n0) = v;
      }
      acc[nt] = zero;
    }
  }
#undef LOADH
#undef COMPH

  __syncthreads();
  // flush Yst -> wsYT: 2560 uint2, fully coalesced
  uint2* gp = reinterpret_cast<uint2*>(wsYT + (size_t)blockIdx.x * (2 * 40 * 128));
  const uint2* lp = reinterpret_cast<const uint2*>(Yst);
#pragma unroll
  for (int it = 0; it < 10; ++it) {
    const int e   = tid + it * 256;
    const int row = e >> 5;
    const int q   = e & 31;
    gp[e] = lp[row * 33 + q];
  }
}

// ---------------------------------------------------------------------------
// k2a: per (chunk c, column n), one lane builds the 8x8 linear-space product
// of CLEN=8 step matrices.  250 blocks x 128 threads (c = blockIdx, n = tid).
// Block 0 also zeroes the k2cb ticket counter (kernel boundary makes it
// visible before k2cb starts; idempotent every call).
// ---------------------------------------------------------------------------
__global__ __launch_bounds__(128, 1) void k2a_chunk(const unsigned short* __restrict__ wsYT,
                                                    float* __restrict__ wsM,
                                                    float* __restrict__ wsScale,
                                                    int* __restrict__ ctr) {
  const int c  = blockIdx.x;
  const int n  = threadIdx.x;
  const int t0 = c * CLEN;
  if (c == 0 && n == 0) *ctr = 0;

  float M[8][8];
  float lsc = 0.f;
  float bufA[40], bufB[40];

#define LOADROW(BUF, TROW) do {                                              \
    const unsigned short* _yr = wsYT + (size_t)(TROW) * (40 * 128) + n;      \
    _Pragma("unroll")                                                        \
    for (int _q = 0; _q < 40; ++_q) BUF[_q] = bf2f(_yr[_q * 128]);           \
  } while (0)

#define INITM(BUF) do {                                                      \
    float _e[40];                                                            \
    _Pragma("unroll")                                                        \
    for (int _q = 0; _q < 40; ++_q) _e[_q] = __expf(BUF[_q]);                \
    _Pragma("unroll")                                                        \
    for (int _i = 0; _i < 4; ++_i)                                           \
      _Pragma("unroll")                                                      \
      for (int _j = 0; _j < 8; ++_j) M[_i][_j] = _e[8*_i+_j];                \
    _Pragma("unroll")                                                        \
    for (int _d = 0; _d < 4; ++_d) {                                         \
      _Pragma("unroll")                                                      \
      for (int _j = 0; _j < 8; ++_j) M[4+_d][_j] = 0.f;                      \
      M[4+_d][_d]   = _e[32+_d];                                             \
      M[4+_d][4+_d] = _e[36+_d];                                             \
    }                                                                        \
  } while (0)

#define STEPM(BUF) do {                                                      \
    float _e[40];                                                            \
    _Pragma("unroll")                                                        \
    for (int _q = 0; _q < 40; ++_q) _e[_q] = __expf(BUF[_q]);                \
    float _nm[8][8];                                                         \
    _Pragma("unroll")                                                        \
    for (int _j = 0; _j < 8; ++_j) {                                         \
      _Pragma("unroll")                                                      \
      for (int _i = 0; _i < 4; ++_i) {                                       \
        float _a = _e[8*_i+0]*M[0][_j] + _e[8*_i+1]*M[1][_j];                \
        float _b = _e[8*_i+2]*M[2][_j] + _e[8*_i+3]*M[3][_j];                \
        float _c = _e[8*_i+4]*M[4][_j] + _e[8*_i+5]*M[5][_j];                \
        float _d = _e[8*_i+6]*M[6][_j] + _e[8*_i+7]*M[7][_j];                \
        _nm[_i][_j] = (_a + _b) + (_c + _d);                                 \
      }                                                                      \
      _Pragma("unroll")                                                      \
      for (int _d2 = 0; _d2 < 4; ++_d2)                                      \
        _nm[4+_d2][_j] = _e[32+_d2]*M[_d2][_j] + _e[36+_d2]*M[4+_d2][_j];    \
    }                                                                        \
    _Pragma("unroll")                                                        \
    for (int _i = 0; _i < 8; ++_i)                                           \
      _Pragma("unroll")                                                      \
      for (int _j = 0; _j < 8; ++_j) M[_i][_j] = _nm[_i][_j];                \
  } while (0)

#define RENORM do {                                                          \
    float _S = 0.f;                                                          \
    _Pragma("unroll")                                                        \
    for (int _i = 0; _i < 8; ++_i)                                           \
      _Pragma("unroll")                                                      \
      for (int _j = 0; _j < 8; ++_j) _S += M[_i][_j];                        \
    lsc += __logf(_S);                                                       \
    const float _inv = 1.0f / _S;                                            \
    _Pragma("unroll")                                                        \
    for (int _i = 0; _i < 8; ++_i)                                           \
      _Pragma("unroll")                                                      \
      for (int _j = 0; _j < 8; ++_j) M[_i][_j] *= _inv;                      \
  } while (0)

  LOADROW(bufA, t0);
  LOADROW(bufB, t0 + 1);
  INITM(bufA);               // row 0
  LOADROW(bufA, t0 + 2);
  STEPM(bufB);               // row 1
  LOADROW(bufB, t0 + 3);
  STEPM(bufA);               // row 2
  LOADROW(bufA, t0 + 4);
  STEPM(bufB);               // row 3
  RENORM;
  LOADROW(bufB, t0 + 5);
  STEPM(bufA);               // row 4
  LOADROW(bufA, t0 + 6);
  STEPM(bufB);               // row 5
  LOADROW(bufB, t0 + 7);
  STEPM(bufA);               // row 6
  STEPM(bufB);               // row 7
  RENORM;

#undef LOADROW
#undef INITM
#undef STEPM
#undef RENORM

  float* dst = wsM + (size_t)(c * N_DIM + n) * 64;
#pragma unroll
  for (int q = 0; q < 16; ++q) {
    float4 v;
    v.x = M[q >> 1][(q & 1) * 4 + 0];
    v.y = M[q >> 1][(q & 1) * 4 + 1];
    v.z = M[q >> 1][(q & 1) * 4 + 2];
    v.w = M[q >> 1][(q & 1) * 4 + 3];
    reinterpret_cast<float4*>(dst)[q] = v;
  }
  wsScale[c * N_DIM + n] = lsc;
}

// ---------------------------------------------------------------------------
// k2cb: fold SLEN=10 chunk matrices into one super-matrix (k2c body), then
// the LAST of the 25 blocks (device-scope ticket; only 25 fences total, vs
// R13's 2000-block storm) folds p0 through all supers -> wsLZ (k2b body).
// ---------------------------------------------------------------------------
__global__ __launch_bounds__(128, 1) void k2cb_super(const float* __restrict__ wsM,
                                                     const float* __restrict__ wsScale,
                                                     float* __restrict__ wsM2,
                                                     float* __restrict__ wsScale2,
                                                     float* __restrict__ wsLZ,
                                                     int* __restrict__ ctr) {
  __shared__ int lastFlag;
  const int sI = blockIdx.x;     // 0..24
  const int n  = threadIdx.x;    // 0..127
  const int c0 = sI * SLEN;

  float A[8][8], B0[8][8], B1[8][8];
  float lsc = 0.f;
#pragma unroll
  for (int u = 0; u < SLEN; ++u) lsc += wsScale[(c0 + u) * N_DIM + n];

#define LOADM(DST, CIDX) do {                                                \
    const float4* _p = reinterpret_cast<const float4*>(                      \
        wsM + (size_t)((CIDX) * N_DIM + n) * 64);                            \
    _Pragma("unroll")                                                        \
    for (int _q = 0; _q < 16; ++_q) {                                        \
      float4 _v = _p[_q];                                                    \
      DST[_q >> 1][(_q & 1) * 4 + 0] = _v.x;                                 \
      DST[_q >> 1][(_q & 1) * 4 + 1] = _v.y;                                 \
      DST[_q >> 1][(_q & 1) * 4 + 2] = _v.z;                                 \
      DST[_q >> 1][(_q & 1) * 4 + 3] = _v.w;                                 \
    }                                                                        \
  } while (0)

#define FOLD(BB) do {                                                        \
    float C[8][8];                                                           \
    _Pragma("unroll")                                                        \
    for (int _i = 0; _i < 8; ++_i)                                           \
      _Pragma("unroll")                                                      \
      for (int _j = 0; _j < 8; ++_j) {                                       \
        float _a = BB[_i][0]*A[0][_j] + BB[_i][1]*A[1][_j];                  \
        float _b = BB[_i][2]*A[2][_j] + BB[_i][3]*A[3][_j];                  \
        float _c = BB[_i][4]*A[4][_j] + BB[_i][5]*A[5][_j];                  \
        float _d = BB[_i][6]*A[6][_j] + BB[_i][7]*A[7][_j];                  \
        C[_i][_j] = (_a + _b) + (_c + _d);                                   \
      }                                                                      \
    float _S = 0.f;                                                          \
    _Pragma("unroll")                                                        \
    for (int _i = 0; _i < 8; ++_i)                                           \
      _Pragma("unroll")                                                      \
      for (int _j = 0; _j < 8; ++_j) _S += C[_i][_j];                        \
    lsc += __logf(_S);                                                       \
    const float _inv = 1.0f / _S;                                            \
    _Pragma("unroll")                                                        \
    for (int _i = 0; _i < 8; ++_i)                                           \
      _Pragma("unroll")                                                      \
      for (int _j = 0; _j < 8; ++_j) A[_i][_j] = C[_i][_j] * _inv;           \
  } while (0)

  LOADM(A, c0);
  LOADM(B0, c0 + 1);
  LOADM(B1, c0 + 2);
  FOLD(B0); LOADM(B0, c0 + 3);
  FOLD(B1); LOADM(B1, c0 + 4);
  FOLD(B0); LOADM(B0, c0 + 5);
  FOLD(B1); LOADM(B1, c0 + 6);
  FOLD(B0); LOADM(B0, c0 + 7);
  FOLD(B1); LOADM(B1, c0 + 8);
  FOLD(B0); LOADM(B0, c0 + 9);
  FOLD(B1);
  FOLD(B0);
#undef LOADM
#undef FOLD

  float* dst = wsM2 + (size_t)(sI * N_DIM + n) * 64;
#pragma unroll
  for (int q = 0; q < 16; ++q) {
    float4 v;
    v.x = A[q >> 1][(q & 1) * 4 + 0];
    v.y = A[q >> 1][(q & 1) * 4 + 1];
    v.z = A[q >> 1][(q & 1) * 4 + 2];
    v.w = A[q >> 1][(q & 1) * 4 + 3];
    reinterpret_cast<float4*>(dst)[q] = v;
  }
  wsScale2[sI * N_DIM + n] = lsc;

  // ---- ticket: last of 25 blocks folds logZ ----
  if (n == 0) {
    __threadfence();
    int old = atomicAdd(ctr, 1);
    lastFlag = (old == NSUPER - 1);
  }
  __syncthreads();
  if (!lastFlag) return;
  __threadfence();

  {
    float p[8] = {1.f, 1.f, 1.f, 1.f, 0.f, 0.f, 0.f, 0.f};
    float lz = 0.f;
#pragma unroll 1
    for (int s = 0; s < NSUPER; ++s) {
      float Ms[8][8];
      const float4* mp = reinterpret_cast<const float4*>(
          wsM2 + (size_t)(s * N_DIM + n) * 64);
#pragma unroll
      for (int q = 0; q < 16; ++q) {
        float4 v = mp[q];
        Ms[q >> 1][(q & 1) * 4 + 0] = v.x; Ms[q >> 1][(q & 1) * 4 + 1] = v.y;
        Ms[q >> 1][(q & 1) * 4 + 2] = v.z; Ms[q >> 1][(q & 1) * 4 + 3] = v.w;
      }
      float np[8];
#pragma unroll
      for (int i = 0; i < 8; ++i) {
        float t0 = Ms[i][0] * p[0] + Ms[i][1] * p[1];
        float t1 = Ms[i][2] * p[2] + Ms[i][3] * p[3];
        float t2 = Ms[i][4] * p[4] + Ms[i][5] * p[5];
        float t3 = Ms[i][6] * p[6] + Ms[i][7] * p[7];
        np[i] = (t0 + t1) + (t2 + t3);
      }
      float S = ((np[0] + np[1]) + (np[2] + np[3])) +
                ((np[4] + np[5]) + (np[6] + np[7]));
      lz += __logf(S) + wsScale2[s * N_DIM + n];
      const float inv = 1.0f / S;
#pragma unroll
      for (int i = 0; i < 8; ++i) p[i] = np[i] * inv;
    }
    wsLZ[n] = lz * (1.0f / (float)T_DIM);
  }
}

// ---------------------------------------------------------------------------
// k3: write the WHOLE output (R12-exact).  Block = 256 rows (2t x 128n);
// each thread builds its row in padded LDS, then a flat coalesced copy with
// NONTEMPORAL stores.
// ---------------------------------------------------------------------------
__global__ __launch_bounds__(256, 3) void k3_out(const unsigned short* __restrict__ wsYT,
                                                 const float* __restrict__ wsMod,
                                                 const float* __restrict__ wsLZ,
                                                 float* __restrict__ out) {
  __shared__ float L[256 * 47];
  const int tid = threadIdx.x;
  const int fr  = blockIdx.x * 256 + tid;
  const int t   = fr >> 7;
  const int n   = fr & 127;
  const float sub = wsLZ[n];

  const unsigned short* yr = wsYT + (size_t)t * (40 * 128) + n;
  float* lrow = &L[tid * 47];
#pragma unroll
  for (int c = 0; c < 40; ++c) lrow[c] = bf2f(yr[c * 128]) - sub;

  const float* mp = wsMod + (size_t)t * (3 * 128) + n;
  const float y40 = mp[0], y41 = mp[128], y42 = mp[256];
  const float m01 = fmaxf(y40, y41);
  const float l01 = m01 + log1pf(__expf(fminf(y40, y41) - m01));
  const float m02 = fmaxf(y40, y42);
  const float l02 = m02 + log1pf(__expf(fminf(y40, y42) - m02));
  lrow[40] = y40 - l01;
  lrow[41] = y41 - l01;
  lrow[42] = y40 - l02;
  lrow[43] = y42 - l02;
  lrow[44] = 0.f;
  lrow[45] = 0.f;
  __syncthreads();

  const size_t base = (size_t)blockIdx.x * (256 * 46);
#pragma unroll
  for (int j = 0; j < 46; ++j) {
    const int e = j * 256 + tid;
    const int r = e / 46;
    const int c = e - r * 46;
    __builtin_nontemporal_store(L[r * 47 + c], &out[base + e]);
  }
}

extern "C" void kernel_launch(void* const* d_in, const int* in_sizes, int n_in,
                              void* d_out, int out_size, void* d_ws, size_t ws_size,
                              hipStream_t stream) {
  (void)in_sizes; (void)n_in; (void)out_size; (void)ws_size;
  const float* x = (const float*)d_in[0];
  const float* W = (const float*)d_in[1];
  const float* b = (const float*)d_in[2];
  float* out = (float*)d_out;

  char* wsb = (char*)d_ws;
  unsigned short* wsYT = (unsigned short*)wsb;               // 2000*40*128 bf16
  float* wsMod   = (float*)(wsb + (size_t)T_DIM * 40 * 128 * 2);   // 2000*3*128 f32
  float* wsM     = wsMod + (size_t)T_DIM * 3 * N_DIM;        // 250*128*64
  float* wsScale = wsM + (size_t)NCHUNK * N_DIM * 64;        // 250*128
  float* wsM2    = wsScale + NCHUNK * N_DIM;                 // 25*128*64
  float* wsScale2= wsM2 + (size_t)NSUPER * N_DIM * 64;       // 25*128
  float* wsLZ    = wsScale2 + NSUPER * N_DIM;                // 128
  int*   wsCtr   = (int*)(wsLZ + N_DIM);                     // 1 int

  hipLaunchKernelGGL(k1_gemm,    dim3(NROWS / 256), dim3(256), 0, stream,
                     x, W, b, wsYT, wsMod);
  hipLaunchKernelGGL(k2a_chunk,  dim3(NCHUNK), dim3(128), 0, stream,
                     wsYT, wsM, wsScale, wsCtr);
  hipLaunchKernelGGL(k2cb_super, dim3(NSUPER), dim3(128), 0, stream,
                     wsM, wsScale, wsM2, wsScale2, wsLZ, wsCtr);
  hipLaunchKernelGGL(k3_out,     dim3(NROWS / 256), dim3(256), 0, stream,
                     wsYT, wsMod, wsLZ, out);
}

// Round 16
// 100.724 us; speedup vs baseline: 1.1784x; 1.1784x over previous
//
#include <hip/hip_runtime.h>

#define T_DIM 2000
#define N_DIM 128
#define IN_DIM 256
#define OUT_C 46
#define NROWS (T_DIM * N_DIM)
#define NCHUNK 250
#define CLEN 8
#define NSUPER 25
#define SLEN 10

typedef short bf16x8 __attribute__((ext_vector_type(8)));
typedef float f32x4 __attribute__((ext_vector_type(4)));

union F8U { bf16x8 v; uint32_t u[4]; };

__device__ __forceinline__ uint32_t cvtpk(float lo, float hi) {
  uint32_t r;
  asm("v_cvt_pk_bf16_f32 %0, %1, %2" : "=v"(r) : "v"(lo), "v"(hi));
  return r;
}

__device__ __forceinline__ float bf2f(unsigned short u) {
  uint32_t w = (uint32_t)u << 16;
  return __builtin_bit_cast(float, w);
}

#define LDSK 264  // padded W row length (shorts)
#define YPAD 132  // padded Yst row length (shorts)

// ---------------------------------------------------------------------------
// k1: y = x @ W^T + b via MFMA 16x16x32 bf16 (W in LDS bf16, half-tile
// ping-pong A prefetch).  Two-PHASE t processing: Yst holds ONE t-value
// (10.6 KB instead of 21.1), flushed after each phase -> total LDS 33.3 KB
// -> 4 blocks/CU (was 3), 16 waves/CU for latency hiding.
// Phase p, wave wv, tile q: rows p*128 + wv*32 + q*16.
// ---------------------------------------------------------------------------
__global__ __launch_bounds__(256, 4) void k1_gemm(const float* __restrict__ x,
                                                  const float* __restrict__ W,
                                                  const float* __restrict__ b,
                                                  unsigned short* __restrict__ wsYT,
                                                  float* __restrict__ wsMod) {
  __shared__ unsigned short Wl[43 * LDSK];   // 22.7 KB
  __shared__ unsigned short Yst[40 * YPAD];  // 10.6 KB (one t-value)
  const int tid  = threadIdx.x;
  const int lane = tid & 63;
  const int wv   = tid >> 6;
  const int ln   = lane & 15;
  const int lh   = lane >> 4;

  {  // stage W as bf16 into padded LDS rows
    uint32_t* Wd = reinterpret_cast<uint32_t*>(Wl);
#pragma unroll
    for (int it = 0; it < 22; ++it) {
      int e = tid + it * 256;
      if (e < 43 * 128) {
        int n = e >> 7, kp = e & 127;
        float2 w = *reinterpret_cast<const float2*>(W + (size_t)n * IN_DIM + 2 * kp);
        Wd[n * (LDSK / 2) + kp] = cvtpk(w.x, w.y);
      }
    }
  }
  float bias[3];
#pragma unroll
  for (int nt = 0; nt < 3; ++nt) {
    int n = nt * 16 + ln;
    bias[nt] = b[n > 42 ? 42 : n];
  }
  __syncthreads();

  const int base = blockIdx.x * 256;
  // wave-local x base; tile k (0..3): row delta = (k>>1)*128 + (k&1)*16
  const float* xbase = x + (size_t)(base + wv * 32 + ln) * IN_DIM + lh * 8;

  f32x4 bufA[8], bufB[8];
  f32x4 zero = {0.f, 0.f, 0.f, 0.f};
  f32x4 acc[3] = {zero, zero, zero};

#define LOADH(BUF, K, HF) do {                                               \
    const float* _p = xbase +                                                \
        (size_t)(((K) >> 1) * 128 + ((K) & 1) * 16) * IN_DIM + (HF) * 128;   \
    _Pragma("unroll")                                                        \
    for (int _s = 0; _s < 4; ++_s) {                                         \
      BUF[_s]     = *reinterpret_cast<const f32x4*>(_p + _s * 32);           \
      BUF[_s + 4] = *reinterpret_cast<const f32x4*>(_p + _s * 32 + 4);       \
    }                                                                        \
  } while (0)

#define COMPH(BUF, HF) do {                                                  \
    _Pragma("unroll")                                                        \
    for (int _s2 = 0; _s2 < 4; ++_s2) {                                      \
      F8U _af;                                                               \
      _af.u[0] = cvtpk(BUF[_s2].x, BUF[_s2].y);                              \
      _af.u[1] = cvtpk(BUF[_s2].z, BUF[_s2].w);                              \
      _af.u[2] = cvtpk(BUF[_s2 + 4].x, BUF[_s2 + 4].y);                      \
      _af.u[3] = cvtpk(BUF[_s2 + 4].z, BUF[_s2 + 4].w);                      \
      const int _s = (HF) * 4 + _s2;                                         \
      _Pragma("unroll")                                                      \
      for (int _nt = 0; _nt < 3; ++_nt) {                                    \
        const bf16x8 _bf = *reinterpret_cast<const bf16x8*>(                 \
            &Wl[(_nt * 16 + ln) * LDSK + _s * 32 + lh * 8]);                 \
        acc[_nt] = __builtin_amdgcn_mfma_f32_16x16x32_bf16(_af.v, _bf,       \
                                                           acc[_nt], 0, 0, 0);\
      }                                                                      \
    }                                                                        \
  } while (0)

  // epilogue for tile K: writes trans scores to Yst, mods to global
#define EPILOG(K) do {                                                       \
    const int _n0 = wv * 32 + ((K) & 1) * 16 + lh * 4;                       \
    _Pragma("unroll")                                                        \
    for (int _nt = 0; _nt < 3; ++_nt) {                                      \
      if (_nt < 2 || ln < 8) {                                               \
        const int _c = _nt * 16 + ln;                                        \
        uint32_t _d0 = cvtpk(acc[_nt][0] + bias[_nt], acc[_nt][1] + bias[_nt]);\
        uint32_t _d1 = cvtpk(acc[_nt][2] + bias[_nt], acc[_nt][3] + bias[_nt]);\
        uint2 _v; _v.x = _d0; _v.y = _d1;                                    \
        *reinterpret_cast<uint2*>(&Yst[_c * YPAD + _n0]) = _v;               \
      } else if (ln < 11) {                                                  \
        const int _tt = blockIdx.x * 2 + ((K) >> 1);                         \
        float4 _v;                                                           \
        _v.x = acc[2][0] + bias[2]; _v.y = acc[2][1] + bias[2];              \
        _v.z = acc[2][2] + bias[2]; _v.w = acc[2][3] + bias[2];              \
        *reinterpret_cast<float4*>(                                          \
            wsMod + ((size_t)_tt * 3 + (ln - 8)) * 128 + _n0) = _v;          \
      }                                                                      \
      acc[_nt] = zero;                                                       \
    }                                                                        \
  } while (0)

  // flush Yst (one t-value) -> wsYT[tt]: 1280 uint2, fully coalesced
#define FLUSH(TT) do {                                                       \
    uint2* _gp = reinterpret_cast<uint2*>(wsYT + (size_t)(TT) * (40 * 128)); \
    const uint2* _lp = reinterpret_cast<const uint2*>(Yst);                  \
    _Pragma("unroll")                                                        \
    for (int _it = 0; _it < 5; ++_it) {                                      \
      const int _e   = tid + _it * 256;                                      \
      const int _row = _e >> 5;                                              \
      const int _q   = _e & 31;                                              \
      _gp[_e] = _lp[_row * 33 + _q];                                         \
    }                                                                        \
  } while (0)

  LOADH(bufA, 0, 0);
  LOADH(bufB, 0, 1);
  // ---- tile 0 (phase 0) ----
  COMPH(bufA, 0); LOADH(bufA, 1, 0);
  COMPH(bufB, 1); LOADH(bufB, 1, 1);
  EPILOG(0);
  // ---- tile 1 (phase 0) ----
  COMPH(bufA, 0); LOADH(bufA, 2, 0);
  COMPH(bufB, 1); LOADH(bufB, 2, 1);
  EPILOG(1);
  __syncthreads();
  FLUSH(blockIdx.x * 2 + 0);
  __syncthreads();
  // ---- tile 2 (phase 1) ----
  COMPH(bufA, 0); LOADH(bufA, 3, 0);
  COMPH(bufB, 1); LOADH(bufB, 3, 1);
  EPILOG(2);
  // ---- tile 3 (phase 1) ----
  COMPH(bufA, 0);
  COMPH(bufB, 1);
  EPILOG(3);
  __syncthreads();
  FLUSH(blockIdx.x * 2 + 1);

#undef LOADH
#undef COMPH
#undef EPILOG
#undef FLUSH
}

// ---------------------------------------------------------------------------
// k2a: per (chunk c, column n), one lane builds the 8x8 linear-space product
// of CLEN=8 step matrices.  250 blocks x 128 threads (c = blockIdx, n = tid).
// ---------------------------------------------------------------------------
__global__ __launch_bounds__(128, 1) void k2a_chunk(const unsigned short* __restrict__ wsYT,
                                                    float* __restrict__ wsM,
                                                    float* __restrict__ wsScale) {
  const int c  = blockIdx.x;
  const int n  = threadIdx.x;
  const int t0 = c * CLEN;

  float M[8][8];
  float lsc = 0.f;
  float bufA[40], bufB[40];

#define LOADROW(BUF, TROW) do {                                              \
    const unsigned short* _yr = wsYT + (size_t)(TROW) * (40 * 128) + n;      \
    _Pragma("unroll")                                                        \
    for (int _q = 0; _q < 40; ++_q) BUF[_q] = bf2f(_yr[_q * 128]);           \
  } while (0)

#define INITM(BUF) do {                                                      \
    float _e[40];                                                            \
    _Pragma("unroll")                                                        \
    for (int _q = 0; _q < 40; ++_q) _e[_q] = __expf(BUF[_q]);                \
    _Pragma("unroll")                                                        \
    for (int _i = 0; _i < 4; ++_i)                                           \
      _Pragma("unroll")                                                      \
      for (int _j = 0; _j < 8; ++_j) M[_i][_j] = _e[8*_i+_j];                \
    _Pragma("unroll")                                                        \
    for (int _d = 0; _d < 4; ++_d) {                                         \
      _Pragma("unroll")                                                      \
      for (int _j = 0; _j < 8; ++_j) M[4+_d][_j] = 0.f;                      \
      M[4+_d][_d]   = _e[32+_d];                                             \
      M[4+_d][4+_d] = _e[36+_d];                                             \
    }                                                                        \
  } while (0)

#define STEPM(BUF) do {                                                      \
    float _e[40];                                                            \
    _Pragma("unroll")                                                        \
    for (int _q = 0; _q < 40; ++_q) _e[_q] = __expf(BUF[_q]);                \
    float _nm[8][8];                                                         \
    _Pragma("unroll")                                                        \
    for (int _j = 0; _j < 8; ++_j) {                                         \
      _Pragma("unroll")                                                      \
      for (int _i = 0; _i < 4; ++_i) {                                       \
        float _a = _e[8*_i+0]*M[0][_j] + _e[8*_i+1]*M[1][_j];                \
        float _b = _e[8*_i+2]*M[2][_j] + _e[8*_i+3]*M[3][_j];                \
        float _c = _e[8*_i+4]*M[4][_j] + _e[8*_i+5]*M[5][_j];                \
        float _d = _e[8*_i+6]*M[6][_j] + _e[8*_i+7]*M[7][_j];                \
        _nm[_i][_j] = (_a + _b) + (_c + _d);                                 \
      }                                                                      \
      _Pragma("unroll")                                                      \
      for (int _d2 = 0; _d2 < 4; ++_d2)                                      \
        _nm[4+_d2][_j] = _e[32+_d2]*M[_d2][_j] + _e[36+_d2]*M[4+_d2][_j];    \
    }                                                                        \
    _Pragma("unroll")                                                        \
    for (int _i = 0; _i < 8; ++_i)                                           \
      _Pragma("unroll")                                                      \
      for (int _j = 0; _j < 8; ++_j) M[_i][_j] = _nm[_i][_j];                \
  } while (0)

#define RENORM do {                                                          \
    float _S = 0.f;                                                          \
    _Pragma("unroll")                                                        \
    for (int _i = 0; _i < 8; ++_i)                                           \
      _Pragma("unroll")                                                      \
      for (int _j = 0; _j < 8; ++_j) _S += M[_i][_j];                        \
    lsc += __logf(_S);                                                       \
    const float _inv = 1.0f / _S;                                            \
    _Pragma("unroll")                                                        \
    for (int _i = 0; _i < 8; ++_i)                                           \
      _Pragma("unroll")                                                      \
      for (int _j = 0; _j < 8; ++_j) M[_i][_j] *= _inv;                      \
  } while (0)

  LOADROW(bufA, t0);
  LOADROW(bufB, t0 + 1);
  INITM(bufA);               // row 0
  LOADROW(bufA, t0 + 2);
  STEPM(bufB);               // row 1
  LOADROW(bufB, t0 + 3);
  STEPM(bufA);               // row 2
  LOADROW(bufA, t0 + 4);
  STEPM(bufB);               // row 3
  RENORM;
  LOADROW(bufB, t0 + 5);
  STEPM(bufA);               // row 4
  LOADROW(bufA, t0 + 6);
  STEPM(bufB);               // row 5
  LOADROW(bufB, t0 + 7);
  STEPM(bufA);               // row 6
  STEPM(bufB);               // row 7
  RENORM;

#undef LOADROW
#undef INITM
#undef STEPM
#undef RENORM

  float* dst = wsM + (size_t)(c * N_DIM + n) * 64;
#pragma unroll
  for (int q = 0; q < 16; ++q) {
    float4 v;
    v.x = M[q >> 1][(q & 1) * 4 + 0];
    v.y = M[q >> 1][(q & 1) * 4 + 1];
    v.z = M[q >> 1][(q & 1) * 4 + 2];
    v.w = M[q >> 1][(q & 1) * 4 + 3];
    reinterpret_cast<float4*>(dst)[q] = v;
  }
  wsScale[c * N_DIM + n] = lsc;
}

// ---------------------------------------------------------------------------
// k2c: fold SLEN=10 chunk matrices into one super-matrix, ping-pong prefetch.
// ---------------------------------------------------------------------------
__global__ __launch_bounds__(128, 1) void k2c_super(const float* __restrict__ wsM,
                                                    const float* __restrict__ wsScale,
                                                    float* __restrict__ wsM2,
                                                    float* __restrict__ wsScale2) {
  const int sI = blockIdx.x;     // 0..24
  const int n  = threadIdx.x;    // 0..127
  const int c0 = sI * SLEN;

  float A[8][8], B0[8][8], B1[8][8];
  float lsc = 0.f;
#pragma unroll
  for (int u = 0; u < SLEN; ++u) lsc += wsScale[(c0 + u) * N_DIM + n];

#define LOADM(DST, CIDX) do {                                                \
    const float4* _p = reinterpret_cast<const float4*>(                      \
        wsM + (size_t)((CIDX) * N_DIM + n) * 64);                            \
    _Pragma("unroll")                                                        \
    for (int _q = 0; _q < 16; ++_q) {                                        \
      float4 _v = _p[_q];                                                    \
      DST[_q >> 1][(_q & 1) * 4 + 0] = _v.x;                                 \
      DST[_q >> 1][(_q & 1) * 4 + 1] = _v.y;                                 \
      DST[_q >> 1][(_q & 1) * 4 + 2] = _v.z;                                 \
      DST[_q >> 1][(_q & 1) * 4 + 3] = _v.w;                                 \
    }                                                                        \
  } while (0)

#define FOLD(BB) do {                                                        \
    float C[8][8];                                                           \
    _Pragma("unroll")                                                        \
    for (int _i = 0; _i < 8; ++_i)                                           \
      _Pragma("unroll")                                                      \
      for (int _j = 0; _j < 8; ++_j) {                                       \
        float _a = BB[_i][0]*A[0][_j] + BB[_i][1]*A[1][_j];                  \
        float _b = BB[_i][2]*A[2][_j] + BB[_i][3]*A[3][_j];                  \
        float _c = BB[_i][4]*A[4][_j] + BB[_i][5]*A[5][_j];                  \
        float _d = BB[_i][6]*A[6][_j] + BB[_i][7]*A[7][_j];                  \
        C[_i][_j] = (_a + _b) + (_c + _d);                                   \
      }                                                                      \
    float _S = 0.f;                                                          \
    _Pragma("unroll")                                                        \
    for (int _i = 0; _i < 8; ++_i)                                           \
      _Pragma("unroll")                                                      \
      for (int _j = 0; _j < 8; ++_j) _S += C[_i][_j];                        \
    lsc += __logf(_S);                                                       \
    const float _inv = 1.0f / _S;                                            \
    _Pragma("unroll")                                                        \
    for (int _i = 0; _i < 8; ++_i)                                           \
      _Pragma("unroll")                                                      \
      for (int _j = 0; _j < 8; ++_j) A[_i][_j] = C[_i][_j] * _inv;           \
  } while (0)

  LOADM(A, c0);
  LOADM(B0, c0 + 1);
  LOADM(B1, c0 + 2);
  FOLD(B0); LOADM(B0, c0 + 3);
  FOLD(B1); LOADM(B1, c0 + 4);
  FOLD(B0); LOADM(B0, c0 + 5);
  FOLD(B1); LOADM(B1, c0 + 6);
  FOLD(B0); LOADM(B0, c0 + 7);
  FOLD(B1); LOADM(B1, c0 + 8);
  FOLD(B0); LOADM(B0, c0 + 9);
  FOLD(B1);
  FOLD(B0);
#undef LOADM
#undef FOLD

  float* dst = wsM2 + (size_t)(sI * N_DIM + n) * 64;
#pragma unroll
  for (int q = 0; q < 16; ++q) {
    float4 v;
    v.x = A[q >> 1][(q & 1) * 4 + 0];
    v.y = A[q >> 1][(q & 1) * 4 + 1];
    v.z = A[q >> 1][(q & 1) * 4 + 2];
    v.w = A[q >> 1][(q & 1) * 4 + 3];
    reinterpret_cast<float4*>(dst)[q] = v;
  }
  wsScale2[sI * N_DIM + n] = lsc;
}

// ---------------------------------------------------------------------------
// k2b: fold p0 through the 25 super-matrices. 8 lanes per column n; all 25
// matrices preloaded into registers (load-level parallelism is the point —
// R15's serial-load merge cost 18us).
// ---------------------------------------------------------------------------
__global__ __launch_bounds__(128, 1) void k2b_fold(const float* __restrict__ wsM2,
                                                   const float* __restrict__ wsScale2,
                                                   float* __restrict__ wsLZ) {
  const int tid = threadIdx.x;
  const int n = blockIdx.x * 16 + (tid >> 3);
  const int i = tid & 7;
  const int gbase = (tid & 63) & ~7;

  float4 r0[NSUPER], r1[NSUPER];
  float sc[NSUPER];
#pragma unroll
  for (int s = 0; s < NSUPER; ++s) {
    const float* Mp = wsM2 + ((size_t)(s * N_DIM + n) * 64 + i * 8);
    r0[s] = *reinterpret_cast<const float4*>(Mp);
    r1[s] = *reinterpret_cast<const float4*>(Mp + 4);
    sc[s] = wsScale2[s * N_DIM + n];
  }

  float p[8] = {1.f, 1.f, 1.f, 1.f, 0.f, 0.f, 0.f, 0.f};
  float lz = 0.f;
#pragma unroll
  for (int s = 0; s < NSUPER; ++s) {
    float np = r0[s].x * p[0] + r0[s].y * p[1] + r0[s].z * p[2] + r0[s].w * p[3]
             + r1[s].x * p[4] + r1[s].y * p[5] + r1[s].z * p[6] + r1[s].w * p[7];
#pragma unroll
    for (int j = 0; j < 8; ++j) p[j] = __shfl(np, gbase + j, 64);
    float S = ((p[0] + p[1]) + (p[2] + p[3])) + ((p[4] + p[5]) + (p[6] + p[7]));
    lz += __logf(S) + sc[s];
    const float inv = 1.0f / S;
#pragma unroll
    for (int j = 0; j < 8; ++j) p[j] *= inv;
  }
  if (i == 0) wsLZ[n] = lz * (1.0f / (float)T_DIM);
}

// ---------------------------------------------------------------------------
// k3: write the WHOLE output (R12-exact).  Block = 256 rows (2t x 128n);
// each thread builds its row in padded LDS, then a flat coalesced copy with
// NONTEMPORAL stores.
// ---------------------------------------------------------------------------
__global__ __launch_bounds__(256, 3) void k3_out(const unsigned short* __restrict__ wsYT,
                                                 const float* __restrict__ wsMod,
                                                 const float* __restrict__ wsLZ,
                                                 float* __restrict__ out) {
  __shared__ float L[256 * 47];
  const int tid = threadIdx.x;
  const int fr  = blockIdx.x * 256 + tid;
  const int t   = fr >> 7;
  const int n   = fr & 127;
  const float sub = wsLZ[n];

  const unsigned short* yr = wsYT + (size_t)t * (40 * 128) + n;
  float* lrow = &L[tid * 47];
#pragma unroll
  for (int c = 0; c < 40; ++c) lrow[c] = bf2f(yr[c * 128]) - sub;

  const float* mp = wsMod + (size_t)t * (3 * 128) + n;
  const float y40 = mp[0], y41 = mp[128], y42 = mp[256];
  const float m01 = fmaxf(y40, y41);
  const float l01 = m01 + log1pf(__expf(fminf(y40, y41) - m01));
  const float m02 = fmaxf(y40, y42);
  const float l02 = m02 + log1pf(__expf(fminf(y40, y42) - m02));
  lrow[40] = y40 - l01;
  lrow[41] = y41 - l01;
  lrow[42] = y40 - l02;
  lrow[43] = y42 - l02;
  lrow[44] = 0.f;
  lrow[45] = 0.f;
  __syncthreads();

  const size_t base = (size_t)blockIdx.x * (256 * 46);
#pragma unroll
  for (int j = 0; j < 46; ++j) {
    const int e = j * 256 + tid;
    const int r = e / 46;
    const int c = e - r * 46;
    __builtin_nontemporal_store(L[r * 47 + c], &out[base + e]);
  }
}

extern "C" void kernel_launch(void* const* d_in, const int* in_sizes, int n_in,
                              void* d_out, int out_size, void* d_ws, size_t ws_size,
                              hipStream_t stream) {
  (void)in_sizes; (void)n_in; (void)out_size; (void)ws_size;
  const float* x = (const float*)d_in[0];
  const float* W = (const float*)d_in[1];
  const float* b = (const float*)d_in[2];
  float* out = (float*)d_out;

  char* wsb = (char*)d_ws;
  unsigned short* wsYT = (unsigned short*)wsb;               // 2000*40*128 bf16
  float* wsMod   = (float*)(wsb + (size_t)T_DIM * 40 * 128 * 2);   // 2000*3*128 f32
  float* wsM     = wsMod + (size_t)T_DIM * 3 * N_DIM;        // 250*128*64
  float* wsScale = wsM + (size_t)NCHUNK * N_DIM * 64;        // 250*128
  float* wsM2    = wsScale + NCHUNK * N_DIM;                 // 25*128*64
  float* wsScale2= wsM2 + (size_t)NSUPER * N_DIM * 64;       // 25*128
  float* wsLZ    = wsScale2 + NSUPER * N_DIM;                // 128

  hipLaunchKernelGGL(k1_gemm,   dim3(NROWS / 256), dim3(256), 0, stream,
                     x, W, b, wsYT, wsMod);
  hipLaunchKernelGGL(k2a_chunk, dim3(NCHUNK), dim3(128), 0, stream,
                     wsYT, wsM, wsScale);
  hipLaunchKernelGGL(k2c_super, dim3(NSUPER), dim3(128), 0, stream,
                     wsM, wsScale, wsM2, wsScale2);
  hipLaunchKernelGGL(k2b_fold,  dim3(8), dim3(128), 0, stream,
                     wsM2, wsScale2, wsLZ);
  hipLaunchKernelGGL(k3_out,    dim3(NROWS / 256), dim3(256), 0, stream,
                     wsYT, wsMod, wsLZ, out);
}